// Round 2
// baseline (1167.260 us; speedup 1.0000x reference)
//
#include <hip/hip_runtime.h>
#include <hip/hip_bf16.h>
#include <cstdint>
#include <cstddef>

#define B_  2
#define S_  2048
#define D_  1024
#define H_  16
#define DH_ 64
#define OUT_ELEMS ((size_t)B_ * S_ * D_)   // 4,194,304; aws follows in d_out

typedef unsigned short u16;
typedef __attribute__((ext_vector_type(8))) short short8;
typedef __attribute__((ext_vector_type(4))) float f32x4;

__device__ __forceinline__ float bf2f(u16 u) {
    union { unsigned int i; float f; } x;
    x.i = ((unsigned int)u) << 16;
    return x.f;
}
__device__ __forceinline__ u16 f2bf(float f) {
    union { float f; unsigned int i; } x; x.f = f;
    unsigned int r = x.i + 0x7fffu + ((x.i >> 16) & 1u);  // round-to-nearest-even
    return (u16)(r >> 16);
}

#define LDSTR 72  // 64 + 8 pad; 144 B row stride (16B-aligned, 2-way bank alias = free)

// ---------------------------------------------------------------------------
// Dtype probe: read even u16s of q. If the data is fp32, these are mantissa
// bits -> as bf16 ~89% are wild (|x|>100, |x|<1e-6, or NaN). If bf16, they
// are real ~N(0,1) values (never wild). flag=1 => external data is fp32.
// ---------------------------------------------------------------------------
__global__ __launch_bounds__(64) void detect_kernel(const void* q, unsigned int* flag)
{
    const int lane = threadIdx.x;
    const u16 e = ((const u16*)q)[lane * 2];
    const float v = bf2f(e);
    const float a = fabsf(v);
    const bool wild = !(a <= 100.f) || (a != 0.f && a < 1e-6f);  // !(a<=100) catches NaN
    unsigned long long m = __ballot(wild);
    if (lane == 0) *flag = (__popcll(m) >= 16) ? 1u : 0u;
}

// ---------------------------------------------------------------------------
// Convert the 4 bias vectors (1024 elems each) to bf16 in ws.
// ---------------------------------------------------------------------------
__global__ __launch_bounds__(256) void convert_bias_kernel(
    const void* bq, const void* bk, const void* bv, const void* bo,
    u16* __restrict__ dst, const unsigned int* __restrict__ flag)
{
    const bool ext32 = flag[0] != 0;
    const int which = blockIdx.y;
    const void* src = which == 0 ? bq : which == 1 ? bk : which == 2 ? bv : bo;
    u16* d = dst + which * 1024;
    const int tid = threadIdx.x;
    #pragma unroll
    for (int i = 0; i < 4; ++i) {
        const int idx = i * 256 + tid;
        d[idx] = ext32 ? f2bf(((const float*)src)[idx]) : ((const u16*)src)[idx];
    }
}

// ---------------------------------------------------------------------------
// Transpose weights into N x K bf16 layout via 64x64 LDS tiles.
// which<3: W (H,D,DH) -> WT[n=h*64+dh][d]   which==3: Wo (D,D) -> WoT[n][d]
// ---------------------------------------------------------------------------
__global__ __launch_bounds__(256) void transpose_weights_kernel(
    const void* Wq, const void* Wk, const void* Wv, const void* Wo,
    u16* __restrict__ WqT, u16* __restrict__ WkT,
    u16* __restrict__ WvT, u16* __restrict__ WoT,
    const unsigned int* __restrict__ flag)
{
    __shared__ u16 t[64][65];
    const bool ext32 = flag[0] != 0;
    const int which = blockIdx.y;
    const void* src = which == 0 ? Wq : which == 1 ? Wk : which == 2 ? Wv : Wo;
    u16* dst = which == 0 ? WqT : which == 1 ? WkT : which == 2 ? WvT : WoT;
    const int tile = blockIdx.x;            // 0..255
    const int tid = threadIdx.x;
    const int rr = tid >> 6;                // 0..3
    const int cc = tid & 63;                // 0..63

    if (which < 3) {
        const int h = tile >> 4, d0 = (tile & 15) * 64;
        #pragma unroll
        for (int i = 0; i < 16; ++i) {
            int r = rr + i * 4;
            size_t idx = ((size_t)(h * 1024 + d0 + r)) * 64 + cc;     // W[h][d0+r][cc]
            t[r][cc] = ext32 ? f2bf(((const float*)src)[idx]) : ((const u16*)src)[idx];
        }
        __syncthreads();
        #pragma unroll
        for (int i = 0; i < 16; ++i) {
            int c = rr + i * 4;  // dh
            dst[((size_t)(h * 64 + c)) * 1024 + d0 + cc] = t[cc][c];  // WT[h*64+c][d0+cc]
        }
    } else {
        const int d0 = (tile >> 4) * 64, n0 = (tile & 15) * 64;
        #pragma unroll
        for (int i = 0; i < 16; ++i) {
            int r = rr + i * 4;
            size_t idx = (size_t)(d0 + r) * 1024 + n0 + cc;           // Wo[d0+r][n0+cc]
            t[r][cc] = ext32 ? f2bf(((const float*)src)[idx]) : ((const u16*)src)[idx];
        }
        __syncthreads();
        #pragma unroll
        for (int i = 0; i < 16; ++i) {
            int c = rr + i * 4;
            dst[(size_t)(n0 + c) * 1024 + d0 + cc] = t[cc][c];        // WoT[n0+c][d0+cc]
        }
    }
}

// ---------------------------------------------------------------------------
// 128x128-tile bf16 MFMA GEMM: out = A(MxK) * BT(NxK)^T + bias(N), N=1024.
// a_ext: A is external (flag dtype); else A is internal bf16.
// mode 0: out[b][h][s][dh] bf16   mode 1: out[b][h][dh][s] bf16
// mode 2: out[m][n] in external dtype (final output)
// ---------------------------------------------------------------------------
__global__ __launch_bounds__(256) void gemm_bias_kernel(
    const void* __restrict__ A, const u16* __restrict__ BT,
    const u16* __restrict__ bias, void* __restrict__ out,
    int M, int K, int mode, int a_ext, const unsigned int* __restrict__ flag)
{
    __shared__ u16 lA[128 * LDSTR];
    __shared__ u16 lB[128 * LDSTR];
    const bool ext32 = flag[0] != 0;
    const int tid = threadIdx.x;
    const int wave = tid >> 6, lane = tid & 63;
    const int m0 = blockIdx.x * 128, n0 = blockIdx.y * 128;
    const int wm = (wave >> 1) * 64, wn = (wave & 1) * 64;

    f32x4 acc[4][4];
    #pragma unroll
    for (int i = 0; i < 4; ++i)
        #pragma unroll
        for (int j = 0; j < 4; ++j)
            acc[i][j] = (f32x4){0.f, 0.f, 0.f, 0.f};

    for (int k0 = 0; k0 < K; k0 += 64) {
        if (a_ext && ext32) {
            const float* Af = (const float*)A;
            #pragma unroll
            for (int it = 0; it < 4; ++it) {
                int e = (it * 256 + tid) * 8;
                int r = e >> 6, c = e & 63;
                const float4 f0 = *(const float4*)&Af[(size_t)(m0 + r) * K + k0 + c];
                const float4 f1 = *(const float4*)&Af[(size_t)(m0 + r) * K + k0 + c + 4];
                short8 o;
                o[0] = (short)f2bf(f0.x); o[1] = (short)f2bf(f0.y);
                o[2] = (short)f2bf(f0.z); o[3] = (short)f2bf(f0.w);
                o[4] = (short)f2bf(f1.x); o[5] = (short)f2bf(f1.y);
                o[6] = (short)f2bf(f1.z); o[7] = (short)f2bf(f1.w);
                *(short8*)&lA[r * LDSTR + c] = o;
                *(short8*)&lB[r * LDSTR + c] = *(const short8*)&BT[(size_t)(n0 + r) * K + k0 + c];
            }
        } else {
            const u16* Ab = (const u16*)A;
            #pragma unroll
            for (int it = 0; it < 4; ++it) {
                int e = (it * 256 + tid) * 8;
                int r = e >> 6, c = e & 63;
                *(short8*)&lA[r * LDSTR + c] = *(const short8*)&Ab[(size_t)(m0 + r) * K + k0 + c];
                *(short8*)&lB[r * LDSTR + c] = *(const short8*)&BT[(size_t)(n0 + r) * K + k0 + c];
            }
        }
        __syncthreads();
        #pragma unroll
        for (int ks = 0; ks < 2; ++ks) {
            const int fk = ((lane >> 4) << 3) + ks * 32;  // quad*8 + kstep
            const int fr = lane & 15;
            short8 af[4], bf[4];
            #pragma unroll
            for (int i = 0; i < 4; ++i) af[i] = *(short8*)&lA[(wm + i * 16 + fr) * LDSTR + fk];
            #pragma unroll
            for (int j = 0; j < 4; ++j) bf[j] = *(short8*)&lB[(wn + j * 16 + fr) * LDSTR + fk];
            #pragma unroll
            for (int i = 0; i < 4; ++i)
                #pragma unroll
                for (int j = 0; j < 4; ++j)
                    acc[i][j] = __builtin_amdgcn_mfma_f32_16x16x32_bf16(af[i], bf[j], acc[i][j], 0, 0, 0);
        }
        __syncthreads();
    }

    const int cf = lane & 15;
    const int rb = (lane >> 4) * 4;
    #pragma unroll
    for (int j = 0; j < 4; ++j) {
        const int n = n0 + wn + j * 16 + cf;
        const float bval = bf2f(bias[n]);
        const int h = n >> 6, dh = n & 63;
        #pragma unroll
        for (int i = 0; i < 4; ++i) {
            #pragma unroll
            for (int reg = 0; reg < 4; ++reg) {
                const int m = m0 + wm + i * 16 + rb + reg;
                const float v = acc[i][j][reg] + bval;
                if (mode == 0) {
                    int b = m >> 11, s = m & (S_ - 1);
                    ((u16*)out)[((size_t)(b * H_ + h) * S_ + s) * DH_ + dh] = f2bf(v);
                } else if (mode == 1) {
                    int b = m >> 11, s = m & (S_ - 1);
                    ((u16*)out)[((size_t)(b * H_ + h) * DH_ + dh) * S_ + s] = f2bf(v);
                } else {
                    size_t off = (size_t)m * D_ + n;
                    if (ext32) ((float*)out)[off] = v;
                    else       ((u16*)out)[off] = f2bf(v);
                }
            }
        }
    }
}

// ---------------------------------------------------------------------------
// Raw scores: per (b,h), S = Q(2048x64) * K(2048x64)^T * 0.125 -> aws region
// of d_out at [h][b][q][k], stored in the external dtype.
// ---------------------------------------------------------------------------
__global__ __launch_bounds__(256) void scores_kernel(
    const u16* __restrict__ Qp, const u16* __restrict__ Kp, void* __restrict__ dout,
    const unsigned int* __restrict__ flag)
{
    __shared__ u16 lA[128 * LDSTR];
    __shared__ u16 lB[128 * LDSTR];
    const bool ext32 = flag[0] != 0;
    const int tid = threadIdx.x;
    const int wave = tid >> 6, lane = tid & 63;
    const int bh = blockIdx.z, b = bh >> 4, h = bh & 15;
    const int m0 = blockIdx.x * 128, n0 = blockIdx.y * 128;
    const int wm = (wave >> 1) * 64, wn = (wave & 1) * 64;
    const u16* Aq = Qp + (size_t)bh * S_ * DH_;
    const u16* Bk = Kp + (size_t)bh * S_ * DH_;

    #pragma unroll
    for (int it = 0; it < 4; ++it) {
        int e = (it * 256 + tid) * 8;
        int r = e >> 6, c = e & 63;
        *(short8*)&lA[r * LDSTR + c] = *(const short8*)&Aq[(size_t)(m0 + r) * DH_ + c];
        *(short8*)&lB[r * LDSTR + c] = *(const short8*)&Bk[(size_t)(n0 + r) * DH_ + c];
    }
    __syncthreads();

    f32x4 acc[4][4];
    #pragma unroll
    for (int i = 0; i < 4; ++i)
        #pragma unroll
        for (int j = 0; j < 4; ++j)
            acc[i][j] = (f32x4){0.f, 0.f, 0.f, 0.f};

    #pragma unroll
    for (int ks = 0; ks < 2; ++ks) {
        const int fk = ((lane >> 4) << 3) + ks * 32;
        const int fr = lane & 15;
        short8 af[4], bf[4];
        #pragma unroll
        for (int i = 0; i < 4; ++i) af[i] = *(short8*)&lA[(wm + i * 16 + fr) * LDSTR + fk];
        #pragma unroll
        for (int j = 0; j < 4; ++j) bf[j] = *(short8*)&lB[(wn + j * 16 + fr) * LDSTR + fk];
        #pragma unroll
        for (int i = 0; i < 4; ++i)
            #pragma unroll
            for (int j = 0; j < 4; ++j)
                acc[i][j] = __builtin_amdgcn_mfma_f32_16x16x32_bf16(af[i], bf[j], acc[i][j], 0, 0, 0);
    }

    const size_t base = (size_t)(h * B_ + b) * S_ * S_;
    const int cf = lane & 15;
    const int rb = (lane >> 4) * 4;
    #pragma unroll
    for (int j = 0; j < 4; ++j) {
        const int n = n0 + wn + j * 16 + cf;
        #pragma unroll
        for (int i = 0; i < 4; ++i) {
            #pragma unroll
            for (int reg = 0; reg < 4; ++reg) {
                const int m = m0 + wm + i * 16 + rb + reg;
                const float v = acc[i][j][reg] * 0.125f;
                if (ext32) ((float*)dout + OUT_ELEMS)[base + (size_t)m * S_ + n] = v;
                else       ((u16*)dout + OUT_ELEMS)[base + (size_t)m * S_ + n] = f2bf(v);
            }
        }
    }
}

// ---------------------------------------------------------------------------
// In-place row softmax over the 2048-wide rows of aws. One block per row.
// ---------------------------------------------------------------------------
__global__ __launch_bounds__(256) void softmax_kernel(
    void* __restrict__ dout, const unsigned int* __restrict__ flag)
{
    const bool ext32 = flag[0] != 0;
    const size_t row = blockIdx.x;
    const int tid = threadIdx.x;
    const int lane = tid & 63, wave = tid >> 6;

    float v[8];
    if (ext32) {
        float* p = (float*)dout + OUT_ELEMS + row * S_;
        const float4 a = *(const float4*)&p[tid * 8];
        const float4 b = *(const float4*)&p[tid * 8 + 4];
        v[0] = a.x; v[1] = a.y; v[2] = a.z; v[3] = a.w;
        v[4] = b.x; v[5] = b.y; v[6] = b.z; v[7] = b.w;
    } else {
        u16* p = (u16*)dout + OUT_ELEMS + row * S_;
        short8 raw = *(short8*)&p[tid * 8];
        #pragma unroll
        for (int e = 0; e < 8; ++e) v[e] = bf2f((u16)raw[e]);
    }

    float mx = v[0];
    #pragma unroll
    for (int e = 1; e < 8; ++e) mx = fmaxf(mx, v[e]);
    #pragma unroll
    for (int off = 32; off > 0; off >>= 1) mx = fmaxf(mx, __shfl_xor(mx, off, 64));

    __shared__ float rmax[4], rsum[4];
    if (lane == 0) rmax[wave] = mx;
    __syncthreads();
    mx = fmaxf(fmaxf(rmax[0], rmax[1]), fmaxf(rmax[2], rmax[3]));

    float s = 0.f;
    #pragma unroll
    for (int e = 0; e < 8; ++e) { v[e] = __expf(v[e] - mx); s += v[e]; }
    #pragma unroll
    for (int off = 32; off > 0; off >>= 1) s += __shfl_xor(s, off, 64);
    if (lane == 0) rsum[wave] = s;
    __syncthreads();
    const float inv = 1.f / (rsum[0] + rsum[1] + rsum[2] + rsum[3]);

    if (ext32) {
        float* p = (float*)dout + OUT_ELEMS + row * S_;
        float4 a, b;
        a.x = v[0] * inv; a.y = v[1] * inv; a.z = v[2] * inv; a.w = v[3] * inv;
        b.x = v[4] * inv; b.y = v[5] * inv; b.z = v[6] * inv; b.w = v[7] * inv;
        *(float4*)&p[tid * 8] = a;
        *(float4*)&p[tid * 8 + 4] = b;
    } else {
        u16* p = (u16*)dout + OUT_ELEMS + row * S_;
        short8 o;
        #pragma unroll
        for (int e = 0; e < 8; ++e) o[e] = (short)f2bf(v[e] * inv);
        *(short8*)&p[tid * 8] = o;
    }
}

// ---------------------------------------------------------------------------
// ctx = aw (2048x2048) * V with B-operand Vt[dh][s] (64 x 2048 bf16).
// Tile 128(M) x 64(N), 2 waves. ctx stored bf16 as [b*s][h*64+dh].
// ---------------------------------------------------------------------------
__global__ __launch_bounds__(128) void ctx_kernel(
    const void* __restrict__ dout, const u16* __restrict__ Vt, u16* __restrict__ ctx,
    const unsigned int* __restrict__ flag)
{
    __shared__ u16 lA[128 * LDSTR];
    __shared__ u16 lB[64 * LDSTR];
    const bool ext32 = flag[0] != 0;
    const int tid = threadIdx.x;
    const int wave = tid >> 6, lane = tid & 63;
    const int bh = blockIdx.z, b = bh >> 4, h = bh & 15;
    const int m0 = blockIdx.x * 128;
    const int wm = wave * 64;
    const size_t abase = (size_t)(h * B_ + b) * S_ * S_;
    const u16* Bv = Vt + (size_t)bh * DH_ * S_;

    f32x4 acc[4][4];
    #pragma unroll
    for (int i = 0; i < 4; ++i)
        #pragma unroll
        for (int j = 0; j < 4; ++j)
            acc[i][j] = (f32x4){0.f, 0.f, 0.f, 0.f};

    for (int k0 = 0; k0 < S_; k0 += 64) {
        if (ext32) {
            const float* Awf = (const float*)dout + OUT_ELEMS + abase;
            #pragma unroll
            for (int it = 0; it < 8; ++it) {
                int e = (it * 128 + tid) * 8;
                int r = e >> 6, c = e & 63;
                const float4 f0 = *(const float4*)&Awf[(size_t)(m0 + r) * S_ + k0 + c];
                const float4 f1 = *(const float4*)&Awf[(size_t)(m0 + r) * S_ + k0 + c + 4];
                short8 o;
                o[0] = (short)f2bf(f0.x); o[1] = (short)f2bf(f0.y);
                o[2] = (short)f2bf(f0.z); o[3] = (short)f2bf(f0.w);
                o[4] = (short)f2bf(f1.x); o[5] = (short)f2bf(f1.y);
                o[6] = (short)f2bf(f1.z); o[7] = (short)f2bf(f1.w);
                *(short8*)&lA[r * LDSTR + c] = o;
            }
        } else {
            const u16* Awb = (const u16*)dout + OUT_ELEMS + abase;
            #pragma unroll
            for (int it = 0; it < 8; ++it) {
                int e = (it * 128 + tid) * 8;
                int r = e >> 6, c = e & 63;
                *(short8*)&lA[r * LDSTR + c] = *(const short8*)&Awb[(size_t)(m0 + r) * S_ + k0 + c];
            }
        }
        #pragma unroll
        for (int it = 0; it < 4; ++it) {
            int e = (it * 128 + tid) * 8;
            int r = e >> 6, c = e & 63;
            *(short8*)&lB[r * LDSTR + c] = *(const short8*)&Bv[(size_t)r * S_ + k0 + c];
        }
        __syncthreads();
        #pragma unroll
        for (int ks = 0; ks < 2; ++ks) {
            const int fk = ((lane >> 4) << 3) + ks * 32;
            const int fr = lane & 15;
            short8 af[4], bf[4];
            #pragma unroll
            for (int i = 0; i < 4; ++i) af[i] = *(short8*)&lA[(wm + i * 16 + fr) * LDSTR + fk];
            #pragma unroll
            for (int j = 0; j < 4; ++j) bf[j] = *(short8*)&lB[(j * 16 + fr) * LDSTR + fk];
            #pragma unroll
            for (int i = 0; i < 4; ++i)
                #pragma unroll
                for (int j = 0; j < 4; ++j)
                    acc[i][j] = __builtin_amdgcn_mfma_f32_16x16x32_bf16(af[i], bf[j], acc[i][j], 0, 0, 0);
        }
        __syncthreads();
    }

    const int cf = lane & 15;
    const int rb = (lane >> 4) * 4;
    #pragma unroll
    for (int j = 0; j < 4; ++j) {
        const int n = j * 16 + cf;  // dh
        #pragma unroll
        for (int i = 0; i < 4; ++i) {
            #pragma unroll
            for (int reg = 0; reg < 4; ++reg) {
                const int m = m0 + wm + i * 16 + rb + reg;  // s
                ctx[((size_t)(b * S_ + m)) * D_ + h * DH_ + n] = f2bf(acc[i][j][reg]);
            }
        }
    }
}

// ---------------------------------------------------------------------------
extern "C" void kernel_launch(void* const* d_in, const int* in_sizes, int n_in,
                              void* d_out, int out_size, void* d_ws, size_t ws_size,
                              hipStream_t stream)
{
    const void* q  = d_in[0];
    const void* k  = d_in[1];
    const void* v  = d_in[2];
    const void* Wq = d_in[3];
    const void* Wk = d_in[4];
    const void* Wv = d_in[5];
    const void* bq = d_in[6];
    const void* bk = d_in[7];
    const void* bv = d_in[8];
    const void* Wo = d_in[9];
    const void* bo = d_in[10];

    u16* ws   = (u16*)d_ws;
    u16* WqT  = ws;                  // 1,048,576 elems
    u16* WkT  = ws + 1048576;
    u16* WvT  = ws + 2097152;
    u16* WoT  = ws + 3145728;
    u16* Qp   = ws + 4194304;        // [b][h][s][dh]; ctx reuses this after scores
    u16* Kp   = ws + 8388608;        // [b][h][s][dh]
    u16* Vt   = ws + 12582912;       // [b][h][dh][s]
    u16* biasB = ws + 16777216;      // bq|bk|bv|bo bf16, 4096 elems
    unsigned int* flag = (unsigned int*)(ws + 16781312);
    u16* ctx  = Qp;                  // [b*s][h*64+dh], overlaps dead Qp

    detect_kernel<<<1, 64, 0, stream>>>(q, flag);
    convert_bias_kernel<<<dim3(1, 4), 256, 0, stream>>>(bq, bk, bv, bo, biasB, flag);
    transpose_weights_kernel<<<dim3(256, 4), 256, 0, stream>>>(
        Wq, Wk, Wv, Wo, WqT, WkT, WvT, WoT, flag);
    gemm_bias_kernel<<<dim3(32, 8), 256, 0, stream>>>(q, WqT, biasB,        Qp, 4096, 1024, 0, 1, flag);
    gemm_bias_kernel<<<dim3(32, 8), 256, 0, stream>>>(k, WkT, biasB + 1024, Kp, 4096, 1024, 0, 1, flag);
    gemm_bias_kernel<<<dim3(32, 8), 256, 0, stream>>>(v, WvT, biasB + 2048, Vt, 4096, 1024, 1, 1, flag);
    scores_kernel<<<dim3(16, 16, 32), 256, 0, stream>>>(Qp, Kp, d_out, flag);
    softmax_kernel<<<dim3(65536), 256, 0, stream>>>(d_out, flag);
    ctx_kernel<<<dim3(16, 1, 32), 128, 0, stream>>>(d_out, Vt, ctx, flag);
    gemm_bias_kernel<<<dim3(32, 8), 256, 0, stream>>>(ctx, WoT, biasB + 3072, d_out, 4096, 1024, 2, 0, flag);
}